// Round 6
// baseline (454.715 us; speedup 1.0000x reference)
//
#include <hip/hip_runtime.h>
#include <hip/hip_bf16.h>
#include <math.h>

#define DMODEL 1024
#define NHEADS 16
#define DKH    64
#define BATCH  2
#define SEQ    2048
#define MROWS  (BATCH * SEQ)   // 4096
#define LOG2E  1.4426950408889634f

typedef __bf16 bf16_t;
typedef bf16_t bf16x8 __attribute__((ext_vector_type(8)));
typedef bf16_t bf16x4 __attribute__((ext_vector_type(4)));
typedef float  floatx4 __attribute__((ext_vector_type(4)));

// async global->LDS, 16B per lane
__device__ __forceinline__ void glds16(const bf16_t* g, bf16_t* l) {
    __builtin_amdgcn_global_load_lds((__attribute__((address_space(1))) unsigned*)(g),
                                     (__attribute__((address_space(3))) unsigned*)(l),
                                     16, 0, 0);
}

// ---------------------------------------------------------------- cast x -> bf16
__global__ void cast_x_kernel(const float* __restrict__ x, bf16_t* __restrict__ xb) {
    int i = (blockIdx.x * 256 + threadIdx.x) * 4;
    float4 v = *(const float4*)(x + i);
    bf16_t o0 = (bf16_t)v.x, o1 = (bf16_t)v.y, o2 = (bf16_t)v.z, o3 = (bf16_t)v.w;
    bf16_t o[4] = {o0, o1, o2, o3};
    *(uint2*)(xb + i) = *(uint2*)o;
}

// --------------------------- 4x W (K x N) -> W^T (N x K) bf16, fused over z
__global__ void transpose4_kernel(const float* __restrict__ W0, const float* __restrict__ W1,
                                  const float* __restrict__ W2, const float* __restrict__ W3,
                                  bf16_t* __restrict__ Wt) {
    __shared__ float t[32][33];
    const float* W = (blockIdx.z == 0) ? W0 : (blockIdx.z == 1) ? W1 : (blockIdx.z == 2) ? W2 : W3;
    bf16_t* dst = Wt + (size_t)blockIdx.z * DMODEL * DMODEL;
    int bx = blockIdx.x, by = blockIdx.y;
    int tx = threadIdx.x, ty = threadIdx.y;
#pragma unroll
    for (int i = 0; i < 32; i += 8)
        t[ty + i][tx] = W[(size_t)(by * 32 + ty + i) * DMODEL + bx * 32 + tx];
    __syncthreads();
#pragma unroll
    for (int i = 0; i < 32; i += 8)
        dst[(size_t)(bx * 32 + ty + i) * DMODEL + by * 32 + tx] = (bf16_t)t[tx][ty + i];
}

// ---------------------------------------------------------------- 128x128 GEMM, BK=64
// MODE 0: fused QKV epilogue. Q -> (b,h,s,d) scaled; K,V -> FRAG-MAJOR layout:
//   frag buffer elem addr = ((bh*32 + kt)*8 + sub)*512 + lane*8 + j
template<int MODE>
__global__ __launch_bounds__(256) void gemm128_kernel(const bf16_t* __restrict__ A,
                                                      const bf16_t* __restrict__ Bt,
                                                      void* __restrict__ outp) {
    __shared__ bf16_t As[128 * 64];
    __shared__ bf16_t Bs[128 * 64];
    int tid = threadIdx.x;
    int w = tid >> 6, l = tid & 63, g = l >> 4, lm = l & 15;
    int wr = w >> 1, wc = w & 1;
    int m0 = blockIdx.y * 128, n0 = blockIdx.x * 128;
    int r8 = l >> 3, s8 = l & 7, cw = s8 ^ r8;

    floatx4 acc[4][4];
#pragma unroll
    for (int i = 0; i < 4; ++i)
#pragma unroll
        for (int j = 0; j < 4; ++j) { floatx4 z = {0.f, 0.f, 0.f, 0.f}; acc[i][j] = z; }

    const bf16_t* Ag = A  + (size_t)(m0 + w * 32 + r8) * DMODEL + cw * 8;
    const bf16_t* Bg = Bt + (size_t)(n0 + w * 32 + r8) * DMODEL + cw * 8;

    for (int k0 = 0; k0 < DMODEL; k0 += 64) {
        __syncthreads();
#pragma unroll
        for (int j = 0; j < 4; ++j) {
            glds16(Ag + (size_t)j * 8 * DMODEL + k0, &As[(w * 32 + j * 8) * 64]);
            glds16(Bg + (size_t)j * 8 * DMODEL + k0, &Bs[(w * 32 + j * 8) * 64]);
        }
        __syncthreads();
#pragma unroll
        for (int kk = 0; kk < 2; ++kk) {
            bf16x8 af[4], bfr[4];
            int c = kk * 4 + g;
            int sw = (c ^ (lm & 7)) * 8;
#pragma unroll
            for (int i = 0; i < 4; ++i) {
                af[i]  = *(const bf16x8*)&As[(wr * 64 + i * 16 + lm) * 64 + sw];
                bfr[i] = *(const bf16x8*)&Bs[(wc * 64 + i * 16 + lm) * 64 + sw];
            }
#pragma unroll
            for (int i = 0; i < 4; ++i)
#pragma unroll
                for (int j = 0; j < 4; ++j)
                    acc[i][j] = __builtin_amdgcn_mfma_f32_16x16x32_bf16(af[i], bfr[j], acc[i][j], 0, 0, 0);
        }
    }

    const size_t NX = (size_t)MROWS * DMODEL;
#pragma unroll
    for (int i = 0; i < 4; ++i) {
#pragma unroll
        for (int j = 0; j < 4; ++j) {
            int nc = n0 + wc * 64 + j * 16 + lm;
            int mb = m0 + wr * 64 + i * 16 + g * 4;
            if (MODE == 0) {
                int mat = n0 >> 10;
                int col = nc & 1023;
                int hh = col >> 6, d = col & 63;
                int b = mb >> 11;
                int bh2 = b * NHEADS + hh;
                int s0 = mb & 2047;
                int kt = s0 >> 6;
                bf16_t* base = (bf16_t*)outp;
                if (mat == 0) {                  // Q (b,h,s,d), scaled log2(e)/8
#pragma unroll
                    for (int r = 0; r < 4; ++r)
                        base[((size_t)bh2 * SEQ + s0 + r) * DKH + d] = (bf16_t)(acc[i][j][r] * (0.125f * LOG2E));
                } else if (mat == 1) {           // K frag-major
                    int kk = d >> 5, gK = (d >> 3) & 3, jK = d & 7;
                    int rt = s0 & 63, mt = rt >> 4, lmK = rt & 15;
                    bf16_t* Kfb = base + NX;
                    size_t tb = (((size_t)bh2 * 32 + kt) * 8 + mt * 2 + kk) * 512 + (gK * 16 + lmK) * 8 + jK;
#pragma unroll
                    for (int r = 0; r < 4; ++r)
                        Kfb[tb + (size_t)r * 8] = (bf16_t)acc[i][j][r];
                } else {                         // V frag-major (from V^T view)
                    int dt = d >> 4, lmV = d & 15;
                    int s63 = s0 & 63;
                    int kkV = s63 >> 5, gV = (s63 >> 3) & 3, jV = s63 & 7;
                    bf16_t* Vfb = base + 2 * NX;
                    size_t tb = (((size_t)bh2 * 32 + kt) * 8 + dt * 2 + kkV) * 512 + (gV * 16 + lmV) * 8 + jV;
                    bf16x4 pk = {(bf16_t)acc[i][j][0], (bf16_t)acc[i][j][1],
                                 (bf16_t)acc[i][j][2], (bf16_t)acc[i][j][3]};
                    *(bf16x4*)&Vfb[tb] = pk;
                }
            } else {
#pragma unroll
                for (int r = 0; r < 4; ++r)
                    ((float*)outp)[(size_t)(mb + r) * DMODEL + nc] = acc[i][j][r];
            }
        }
    }
}

// ---------------------------------------------------------------- O-proj GEMM, 64x128 tile
// grid (N/128, M/64) = (8, 64) = 512 blocks -> 2 blocks/CU. fp32 row-major out.
__global__ __launch_bounds__(256) void gemmO_kernel(const bf16_t* __restrict__ A,
                                                    const bf16_t* __restrict__ Bt,
                                                    float* __restrict__ outp) {
    __shared__ bf16_t As[64 * 64];
    __shared__ bf16_t Bs[128 * 64];
    int tid = threadIdx.x;
    int w = tid >> 6, l = tid & 63, g = l >> 4, lm = l & 15;
    int wr = w & 1, wc = w >> 1;
    int m0 = blockIdx.y * 64, n0 = blockIdx.x * 128;
    int r8 = l >> 3, s8 = l & 7, cw = s8 ^ r8;

    floatx4 acc[2][4];
#pragma unroll
    for (int i = 0; i < 2; ++i)
#pragma unroll
        for (int j = 0; j < 4; ++j) { floatx4 z = {0.f, 0.f, 0.f, 0.f}; acc[i][j] = z; }

    const bf16_t* Ag = A  + (size_t)(m0 + w * 16 + r8) * DMODEL + cw * 8;
    const bf16_t* Bg = Bt + (size_t)(n0 + w * 32 + r8) * DMODEL + cw * 8;

    for (int k0 = 0; k0 < DMODEL; k0 += 64) {
        __syncthreads();
#pragma unroll
        for (int j = 0; j < 2; ++j)
            glds16(Ag + (size_t)j * 8 * DMODEL + k0, &As[(w * 16 + j * 8) * 64]);
#pragma unroll
        for (int j = 0; j < 4; ++j)
            glds16(Bg + (size_t)j * 8 * DMODEL + k0, &Bs[(w * 32 + j * 8) * 64]);
        __syncthreads();
#pragma unroll
        for (int kk = 0; kk < 2; ++kk) {
            bf16x8 af[2], bfr[4];
            int c = kk * 4 + g;
            int sw = (c ^ (lm & 7)) * 8;
#pragma unroll
            for (int i = 0; i < 2; ++i)
                af[i] = *(const bf16x8*)&As[(wr * 32 + i * 16 + lm) * 64 + sw];
#pragma unroll
            for (int j = 0; j < 4; ++j)
                bfr[j] = *(const bf16x8*)&Bs[(wc * 64 + j * 16 + lm) * 64 + sw];
#pragma unroll
            for (int i = 0; i < 2; ++i)
#pragma unroll
                for (int j = 0; j < 4; ++j)
                    acc[i][j] = __builtin_amdgcn_mfma_f32_16x16x32_bf16(af[i], bfr[j], acc[i][j], 0, 0, 0);
        }
    }

#pragma unroll
    for (int i = 0; i < 2; ++i)
#pragma unroll
        for (int j = 0; j < 4; ++j) {
            int nc = n0 + wc * 64 + j * 16 + lm;
            int mb = m0 + wr * 32 + i * 16 + g * 4;
#pragma unroll
            for (int r = 0; r < 4; ++r)
                outp[(size_t)(mb + r) * DMODEL + nc] = acc[i][j][r];
        }
}

// ---------------------------------------------------------------- fused flash attention
// grid (32 bh, 32 qblk), block 256 = 4 waves = 4-way KEY SPLIT over the same 64 q rows.
// Wave: 64 q x 512 keys (8 iters). K/V frag-major coalesced loads; K reg-double-buffered;
// no barriers in K-loop. 4 partials merged via LDS tree (2 d-passes, every wave does 1/4).
__global__ __launch_bounds__(256, 4) void attn_kernel(const bf16_t* __restrict__ Q,
                                                      const bf16_t* __restrict__ Kf,
                                                      const bf16_t* __restrict__ Vf,
                                                      bf16_t* __restrict__ Cc) {
    __shared__ __align__(16) char smem[37888];
    bf16_t* Ps   = (bf16_t*)smem;            // [w][4096] wave-private P tiles (loop phase)
    float*  Mbuf = (float*)smem;             // [w][64*36] merge partials (aliased, after loop)
    float*  Lbuf = (float*)(smem + 36864);   // [w][64] lsum partials

    int tid = threadIdx.x;
    int w = tid >> 6, l = tid & 63, g = l >> 4, lm = l & 15;
    int bh = blockIdx.x, b = bh >> 4, h = bh & 15;
    int q0 = blockIdx.y * 64;
    int xsw = lm & 14;

    const bf16_t* Qh  = Q  + ((size_t)bh * SEQ + q0) * DKH;
    const bf16_t* Kfh = Kf + (size_t)bh * 32 * 8 * 512 + l * 8;
    const bf16_t* Vfh = Vf + (size_t)bh * 32 * 8 * 512 + l * 8;

    // Q as B-frags (loaded once; all 4 waves same 64 q rows)
    bf16x8 qf[4][2];
#pragma unroll
    for (int nt = 0; nt < 4; ++nt)
#pragma unroll
        for (int kk = 0; kk < 2; ++kk)
            qf[nt][kk] = *(const bf16x8*)(Qh + (size_t)(nt * 16 + lm) * DKH + kk * 32 + g * 8);

    floatx4 oacc[4][4];
#pragma unroll
    for (int dt = 0; dt < 4; ++dt)
#pragma unroll
        for (int nt = 0; nt < 4; ++nt) { floatx4 z = {0.f, 0.f, 0.f, 0.f}; oacc[dt][nt] = z; }
    float lsum[4] = {0.f, 0.f, 0.f, 0.f};

    int kt0 = w * 8;                          // this wave's key range: 8 tiles of 64
    bf16x8 kf[4][2], kfn[4][2], vf[4][2];
#pragma unroll
    for (int mt = 0; mt < 4; ++mt)
#pragma unroll
        for (int kk = 0; kk < 2; ++kk)
            kf[mt][kk] = *(const bf16x8*)(Kfh + ((size_t)kt0 * 8 + mt * 2 + kk) * 512);

#pragma unroll 2
    for (int it = 0; it < 8; ++it) {
        int kt = kt0 + it;
        const bf16_t* Vt = Vfh + (size_t)kt * 8 * 512;

#pragma unroll
        for (int dt = 0; dt < 4; ++dt)
#pragma unroll
            for (int kk = 0; kk < 2; ++kk)
                vf[dt][kk] = *(const bf16x8*)(Vt + (dt * 2 + kk) * 512);

        // S^T = K * Q^T
        floatx4 sacc[4][4];
#pragma unroll
        for (int mt = 0; mt < 4; ++mt)
#pragma unroll
            for (int nt = 0; nt < 4; ++nt) { floatx4 z = {0.f, 0.f, 0.f, 0.f}; sacc[mt][nt] = z; }
#pragma unroll
        for (int kk = 0; kk < 2; ++kk)
#pragma unroll
            for (int mt = 0; mt < 4; ++mt)
#pragma unroll
                for (int nt = 0; nt < 4; ++nt)
                    sacc[mt][nt] = __builtin_amdgcn_mfma_f32_16x16x32_bf16(kf[mt][kk], qf[nt][kk], sacc[mt][nt], 0, 0, 0);

        // prefetch next iter's K frags
        int ktn = (it < 7) ? kt + 1 : kt0;
        const bf16_t* Kn = Kfh + (size_t)ktn * 8 * 512;
#pragma unroll
        for (int mt = 0; mt < 4; ++mt)
#pragma unroll
            for (int kk = 0; kk < 2; ++kk)
                kfn[mt][kk] = *(const bf16x8*)(Kn + (mt * 2 + kk) * 512);

        // exp2 + lsum + packed b64 P write (wave-private, swizzled)
#pragma unroll
        for (int mt = 0; mt < 4; ++mt)
#pragma unroll
            for (int nt = 0; nt < 4; ++nt) {
                float p0 = __builtin_amdgcn_exp2f(sacc[mt][nt][0]);
                float p1 = __builtin_amdgcn_exp2f(sacc[mt][nt][1]);
                float p2 = __builtin_amdgcn_exp2f(sacc[mt][nt][2]);
                float p3 = __builtin_amdgcn_exp2f(sacc[mt][nt][3]);
                lsum[nt] += (p0 + p1) + (p2 + p3);
                bf16x4 pk = {(bf16_t)p0, (bf16_t)p1, (bf16_t)p2, (bf16_t)p3};
                *(bf16x4*)&Ps[w * 4096 + (nt * 16 + lm) * 64 + (((mt * 4 + g) ^ xsw) << 2)] = pk;
            }

        // O^T += V^T * P^T
#pragma unroll
        for (int kk = 0; kk < 2; ++kk) {
            bf16x8 bp[4];
#pragma unroll
            for (int nt = 0; nt < 4; ++nt)
                bp[nt] = *(const bf16x8*)&Ps[w * 4096 + (nt * 16 + lm) * 64 + (((kk * 8 + g * 2) ^ xsw) << 2)];
#pragma unroll
            for (int dt = 0; dt < 4; ++dt)
#pragma unroll
                for (int nt = 0; nt < 4; ++nt)
                    oacc[dt][nt] = __builtin_amdgcn_mfma_f32_16x16x32_bf16(vf[dt][kk], bp[nt], oacc[dt][nt], 0, 0, 0);
        }

        // rotate K double-buffer
#pragma unroll
        for (int mt = 0; mt < 4; ++mt)
#pragma unroll
            for (int kk = 0; kk < 2; ++kk)
                kf[mt][kk] = kfn[mt][kk];
    }

    // reduce lsum within wave across g-groups
#pragma unroll
    for (int nt = 0; nt < 4; ++nt) {
        float s = lsum[nt];
        s += __shfl_xor(s, 16, 64);
        s += __shfl_xor(s, 32, 64);
        lsum[nt] = s;
    }

    // 4-partial merge through LDS (2 d-passes; every wave sums its q-quarter)
    float linv = 0.f;
#pragma unroll
    for (int p = 0; p < 2; ++p) {
        __syncthreads();
#pragma unroll
        for (int dh = 0; dh < 2; ++dh) {
            int dt = p * 2 + dh;
#pragma unroll
            for (int nt = 0; nt < 4; ++nt)
                *(floatx4*)&Mbuf[w * 2304 + (nt * 16 + lm) * 36 + dh * 16 + g * 4] = oacc[dt][nt];
        }
        if (p == 0 && g == 0)
#pragma unroll
            for (int nt = 0; nt < 4; ++nt)
                Lbuf[w * 64 + nt * 16 + lm] = lsum[nt];
        __syncthreads();
        if (p == 0) {
            float lt = 0.f;
#pragma unroll
            for (int w2 = 0; w2 < 4; ++w2)
                lt += Lbuf[w2 * 64 + w * 16 + lm];
            linv = 1.0f / lt;
        }
#pragma unroll
        for (int cc = 0; cc < 2; ++cc) {
            floatx4 s = {0.f, 0.f, 0.f, 0.f};
#pragma unroll
            for (int w2 = 0; w2 < 4; ++w2)
                s += *(const floatx4*)&Mbuf[w2 * 2304 + (w * 16 + lm) * 36 + cc * 16 + g * 4];
            bf16x4 pk = {(bf16_t)(s[0] * linv), (bf16_t)(s[1] * linv),
                         (bf16_t)(s[2] * linv), (bf16_t)(s[3] * linv)};
            int q = q0 + w * 16 + lm;
            int d = h * DKH + p * 32 + cc * 16 + g * 4;
            *(bf16x4*)&Cc[((size_t)(b * SEQ + q)) * DMODEL + d] = pk;
        }
    }
}

// ----------------------------------------------------------------------------
extern "C" void kernel_launch(void* const* d_in, const int* in_sizes, int n_in,
                              void* d_out, int out_size, void* d_ws, size_t ws_size,
                              hipStream_t stream) {
    const float* x  = (const float*)d_in[0];
    const float* Wq = (const float*)d_in[1];
    const float* Wk = (const float*)d_in[2];
    const float* Wv = (const float*)d_in[3];
    const float* Wo = (const float*)d_in[4];

    const size_t NX = (size_t)MROWS * DMODEL;
    const size_t NW = (size_t)DMODEL * DMODEL;
    bf16_t* ws  = (bf16_t*)d_ws;
    bf16_t* xb  = ws;            // x bf16
    bf16_t* Wt  = xb + NX;       // W^T x4 contiguous: q,k,v,o
    bf16_t* Wto = Wt + 3 * NW;
    bf16_t* Qb  = Wt + 4 * NW;   // Q (b,h,s,d), scaled log2(e)/8
    bf16_t* Kfb = Qb + NX;       // K frag-major
    bf16_t* Vfb = Kfb + NX;      // V frag-major
    bf16_t* Cc  = Vfb + NX;      // concat

    cast_x_kernel<<<NX / 1024, 256, 0, stream>>>(x, xb);
    transpose4_kernel<<<dim3(32, 32, 4), dim3(32, 8), 0, stream>>>(Wq, Wk, Wv, Wo, Wt);

    gemm128_kernel<0><<<dim3(3 * DMODEL / 128, MROWS / 128), 256, 0, stream>>>(xb, Wt, Qb);

    attn_kernel<<<dim3(BATCH * NHEADS, SEQ / 64), 256, 0, stream>>>(Qb, Kfb, Vfb, Cc);

    gemmO_kernel<<<dim3(DMODEL / 128, MROWS / 64), 256, 0, stream>>>(Cc, Wto, (float*)d_out);
}

// Round 7
// 195.420 us; speedup vs baseline: 2.3269x; 2.3269x over previous
//
#include <hip/hip_runtime.h>
#include <hip/hip_bf16.h>
#include <math.h>

#define DMODEL 1024
#define NHEADS 16
#define DKH    64
#define BATCH  2
#define SEQ    2048
#define MROWS  (BATCH * SEQ)   // 4096
#define LOG2E  1.4426950408889634f

typedef __bf16 bf16_t;
typedef bf16_t bf16x8 __attribute__((ext_vector_type(8)));
typedef bf16_t bf16x4 __attribute__((ext_vector_type(4)));
typedef float  floatx4 __attribute__((ext_vector_type(4)));

// async global->LDS, 16B per lane
__device__ __forceinline__ void glds16(const bf16_t* g, bf16_t* l) {
    __builtin_amdgcn_global_load_lds((__attribute__((address_space(1))) unsigned*)(g),
                                     (__attribute__((address_space(3))) unsigned*)(l),
                                     16, 0, 0);
}

// ---------------------------------------------------------------- cast x -> bf16
__global__ void cast_x_kernel(const float* __restrict__ x, bf16_t* __restrict__ xb) {
    int i = (blockIdx.x * 256 + threadIdx.x) * 4;
    float4 v = *(const float4*)(x + i);
    bf16_t o0 = (bf16_t)v.x, o1 = (bf16_t)v.y, o2 = (bf16_t)v.z, o3 = (bf16_t)v.w;
    bf16_t o[4] = {o0, o1, o2, o3};
    *(uint2*)(xb + i) = *(uint2*)o;
}

// --------------------------- 4x W (K x N) -> W^T (N x K) bf16, fused over z
__global__ void transpose4_kernel(const float* __restrict__ W0, const float* __restrict__ W1,
                                  const float* __restrict__ W2, const float* __restrict__ W3,
                                  bf16_t* __restrict__ Wt) {
    __shared__ float t[32][33];
    const float* W = (blockIdx.z == 0) ? W0 : (blockIdx.z == 1) ? W1 : (blockIdx.z == 2) ? W2 : W3;
    bf16_t* dst = Wt + (size_t)blockIdx.z * DMODEL * DMODEL;
    int bx = blockIdx.x, by = blockIdx.y;
    int tx = threadIdx.x, ty = threadIdx.y;
#pragma unroll
    for (int i = 0; i < 32; i += 8)
        t[ty + i][tx] = W[(size_t)(by * 32 + ty + i) * DMODEL + bx * 32 + tx];
    __syncthreads();
#pragma unroll
    for (int i = 0; i < 32; i += 8)
        dst[(size_t)(bx * 32 + ty + i) * DMODEL + by * 32 + tx] = (bf16_t)t[tx][ty + i];
}

// ---------------------------------------------------------------- 128x128 GEMM, BK=64
// MODE 0: fused QKV epilogue. Q -> (b,h,s,d) scaled; K,V -> FRAG-MAJOR layout:
//   frag buffer elem addr = ((bh*32 + kt)*8 + sub)*512 + lane*8 + j
template<int MODE>
__global__ __launch_bounds__(256) void gemm128_kernel(const bf16_t* __restrict__ A,
                                                      const bf16_t* __restrict__ Bt,
                                                      void* __restrict__ outp) {
    __shared__ bf16_t As[128 * 64];
    __shared__ bf16_t Bs[128 * 64];
    int tid = threadIdx.x;
    int w = tid >> 6, l = tid & 63, g = l >> 4, lm = l & 15;
    int wr = w >> 1, wc = w & 1;
    int m0 = blockIdx.y * 128, n0 = blockIdx.x * 128;
    int r8 = l >> 3, s8 = l & 7, cw = s8 ^ r8;

    floatx4 acc[4][4];
#pragma unroll
    for (int i = 0; i < 4; ++i)
#pragma unroll
        for (int j = 0; j < 4; ++j) { floatx4 z = {0.f, 0.f, 0.f, 0.f}; acc[i][j] = z; }

    const bf16_t* Ag = A  + (size_t)(m0 + w * 32 + r8) * DMODEL + cw * 8;
    const bf16_t* Bg = Bt + (size_t)(n0 + w * 32 + r8) * DMODEL + cw * 8;

    for (int k0 = 0; k0 < DMODEL; k0 += 64) {
        __syncthreads();
#pragma unroll
        for (int j = 0; j < 4; ++j) {
            glds16(Ag + (size_t)j * 8 * DMODEL + k0, &As[(w * 32 + j * 8) * 64]);
            glds16(Bg + (size_t)j * 8 * DMODEL + k0, &Bs[(w * 32 + j * 8) * 64]);
        }
        __syncthreads();
#pragma unroll
        for (int kk = 0; kk < 2; ++kk) {
            bf16x8 af[4], bfr[4];
            int c = kk * 4 + g;
            int sw = (c ^ (lm & 7)) * 8;
#pragma unroll
            for (int i = 0; i < 4; ++i) {
                af[i]  = *(const bf16x8*)&As[(wr * 64 + i * 16 + lm) * 64 + sw];
                bfr[i] = *(const bf16x8*)&Bs[(wc * 64 + i * 16 + lm) * 64 + sw];
            }
#pragma unroll
            for (int i = 0; i < 4; ++i)
#pragma unroll
                for (int j = 0; j < 4; ++j)
                    acc[i][j] = __builtin_amdgcn_mfma_f32_16x16x32_bf16(af[i], bfr[j], acc[i][j], 0, 0, 0);
        }
    }

    const size_t NX = (size_t)MROWS * DMODEL;
#pragma unroll
    for (int i = 0; i < 4; ++i) {
#pragma unroll
        for (int j = 0; j < 4; ++j) {
            int nc = n0 + wc * 64 + j * 16 + lm;
            int mb = m0 + wr * 64 + i * 16 + g * 4;
            if (MODE == 0) {
                int mat = n0 >> 10;
                int col = nc & 1023;
                int hh = col >> 6, d = col & 63;
                int b = mb >> 11;
                int bh2 = b * NHEADS + hh;
                int s0 = mb & 2047;
                int kt = s0 >> 6;
                bf16_t* base = (bf16_t*)outp;
                if (mat == 0) {                  // Q (b,h,s,d), scaled log2(e)/8
#pragma unroll
                    for (int r = 0; r < 4; ++r)
                        base[((size_t)bh2 * SEQ + s0 + r) * DKH + d] = (bf16_t)(acc[i][j][r] * (0.125f * LOG2E));
                } else if (mat == 1) {           // K frag-major
                    int kk = d >> 5, gK = (d >> 3) & 3, jK = d & 7;
                    int rt = s0 & 63, mt = rt >> 4, lmK = rt & 15;
                    bf16_t* Kfb = base + NX;
                    size_t tb = (((size_t)bh2 * 32 + kt) * 8 + mt * 2 + kk) * 512 + (gK * 16 + lmK) * 8 + jK;
#pragma unroll
                    for (int r = 0; r < 4; ++r)
                        Kfb[tb + (size_t)r * 8] = (bf16_t)acc[i][j][r];
                } else {                         // V frag-major (from V^T view)
                    int dt = d >> 4, lmV = d & 15;
                    int s63 = s0 & 63;
                    int kkV = s63 >> 5, gV = (s63 >> 3) & 3, jV = s63 & 7;
                    bf16_t* Vfb = base + 2 * NX;
                    size_t tb = (((size_t)bh2 * 32 + kt) * 8 + dt * 2 + kkV) * 512 + (gV * 16 + lmV) * 8 + jV;
                    bf16x4 pk = {(bf16_t)acc[i][j][0], (bf16_t)acc[i][j][1],
                                 (bf16_t)acc[i][j][2], (bf16_t)acc[i][j][3]};
                    *(bf16x4*)&Vfb[tb] = pk;
                }
            } else {
#pragma unroll
                for (int r = 0; r < 4; ++r)
                    ((float*)outp)[(size_t)(mb + r) * DMODEL + nc] = acc[i][j][r];
            }
        }
    }
}

// ---------------------------------------------------------------- O-proj GEMM, 64x128 tile
// grid (N/128, M/64) = (8, 64) = 512 blocks -> 2 blocks/CU. fp32 row-major out.
__global__ __launch_bounds__(256) void gemmO_kernel(const bf16_t* __restrict__ A,
                                                    const bf16_t* __restrict__ Bt,
                                                    float* __restrict__ outp) {
    __shared__ bf16_t As[64 * 64];
    __shared__ bf16_t Bs[128 * 64];
    int tid = threadIdx.x;
    int w = tid >> 6, l = tid & 63, g = l >> 4, lm = l & 15;
    int wr = w & 1, wc = w >> 1;
    int m0 = blockIdx.y * 64, n0 = blockIdx.x * 128;
    int r8 = l >> 3, s8 = l & 7, cw = s8 ^ r8;

    floatx4 acc[2][4];
#pragma unroll
    for (int i = 0; i < 2; ++i)
#pragma unroll
        for (int j = 0; j < 4; ++j) { floatx4 z = {0.f, 0.f, 0.f, 0.f}; acc[i][j] = z; }

    const bf16_t* Ag = A  + (size_t)(m0 + w * 16 + r8) * DMODEL + cw * 8;
    const bf16_t* Bg = Bt + (size_t)(n0 + w * 32 + r8) * DMODEL + cw * 8;

    for (int k0 = 0; k0 < DMODEL; k0 += 64) {
        __syncthreads();
#pragma unroll
        for (int j = 0; j < 2; ++j)
            glds16(Ag + (size_t)j * 8 * DMODEL + k0, &As[(w * 16 + j * 8) * 64]);
#pragma unroll
        for (int j = 0; j < 4; ++j)
            glds16(Bg + (size_t)j * 8 * DMODEL + k0, &Bs[(w * 32 + j * 8) * 64]);
        __syncthreads();
#pragma unroll
        for (int kk = 0; kk < 2; ++kk) {
            bf16x8 af[2], bfr[4];
            int c = kk * 4 + g;
            int sw = (c ^ (lm & 7)) * 8;
#pragma unroll
            for (int i = 0; i < 2; ++i)
                af[i] = *(const bf16x8*)&As[(wr * 32 + i * 16 + lm) * 64 + sw];
#pragma unroll
            for (int j = 0; j < 4; ++j)
                bfr[j] = *(const bf16x8*)&Bs[(wc * 64 + j * 16 + lm) * 64 + sw];
#pragma unroll
            for (int i = 0; i < 2; ++i)
#pragma unroll
                for (int j = 0; j < 4; ++j)
                    acc[i][j] = __builtin_amdgcn_mfma_f32_16x16x32_bf16(af[i], bfr[j], acc[i][j], 0, 0, 0);
        }
    }

#pragma unroll
    for (int i = 0; i < 2; ++i)
#pragma unroll
        for (int j = 0; j < 4; ++j) {
            int nc = n0 + wc * 64 + j * 16 + lm;
            int mb = m0 + wr * 32 + i * 16 + g * 4;
#pragma unroll
            for (int r = 0; r < 4; ++r)
                outp[(size_t)(mb + r) * DMODEL + nc] = acc[i][j][r];
        }
}

// ---------------------------------------------------------------- fused flash attention
// grid (32 bh, 32 qblk), block 256 = 4 waves = 4-way KEY SPLIT over the same 64 q rows.
// Wave: 64 q x 512 keys (8 iters). K/V frag-major coalesced loads; K reg-double-buffered;
// no barriers in K-loop. 4 partials merged via LDS tree.
// __launch_bounds__(256,2): R5-proven 128-VGPR allocation (cap 256, compiler lands 128).
// At 128 VGPR + 37.9 KB LDS the HW residency limit is 4 blocks/CU — grid supplies them.
// DO NOT use (256,4): compiler caps VGPR at 64 and spills ~1.5 GB/launch (R6: 320 us).
__global__ __launch_bounds__(256, 2) void attn_kernel(const bf16_t* __restrict__ Q,
                                                      const bf16_t* __restrict__ Kf,
                                                      const bf16_t* __restrict__ Vf,
                                                      bf16_t* __restrict__ Cc) {
    __shared__ __align__(16) char smem[37888];
    bf16_t* Ps   = (bf16_t*)smem;            // [w][4096] wave-private P tiles (loop phase)
    float*  Mbuf = (float*)smem;             // [w][64*36] merge partials (aliased, after loop)
    float*  Lbuf = (float*)(smem + 36864);   // [w][64] lsum partials

    int tid = threadIdx.x;
    int w = tid >> 6, l = tid & 63, g = l >> 4, lm = l & 15;
    int bh = blockIdx.x, b = bh >> 4, h = bh & 15;
    int q0 = blockIdx.y * 64;
    int xsw = lm & 14;

    const bf16_t* Qh  = Q  + ((size_t)bh * SEQ + q0) * DKH;
    const bf16_t* Kfh = Kf + (size_t)bh * 32 * 8 * 512 + l * 8;
    const bf16_t* Vfh = Vf + (size_t)bh * 32 * 8 * 512 + l * 8;

    // Q as B-frags (loaded once; all 4 waves same 64 q rows)
    bf16x8 qf[4][2];
#pragma unroll
    for (int nt = 0; nt < 4; ++nt)
#pragma unroll
        for (int kk = 0; kk < 2; ++kk)
            qf[nt][kk] = *(const bf16x8*)(Qh + (size_t)(nt * 16 + lm) * DKH + kk * 32 + g * 8);

    floatx4 oacc[4][4];
#pragma unroll
    for (int dt = 0; dt < 4; ++dt)
#pragma unroll
        for (int nt = 0; nt < 4; ++nt) { floatx4 z = {0.f, 0.f, 0.f, 0.f}; oacc[dt][nt] = z; }
    float lsum[4] = {0.f, 0.f, 0.f, 0.f};

    int kt0 = w * 8;                          // this wave's key range: 8 tiles of 64
    bf16x8 kf[4][2], kfn[4][2], vf[4][2];
#pragma unroll
    for (int mt = 0; mt < 4; ++mt)
#pragma unroll
        for (int kk = 0; kk < 2; ++kk)
            kf[mt][kk] = *(const bf16x8*)(Kfh + ((size_t)kt0 * 8 + mt * 2 + kk) * 512);

#pragma unroll 2
    for (int it = 0; it < 8; ++it) {
        int kt = kt0 + it;
        const bf16_t* Vt = Vfh + (size_t)kt * 8 * 512;

#pragma unroll
        for (int dt = 0; dt < 4; ++dt)
#pragma unroll
            for (int kk = 0; kk < 2; ++kk)
                vf[dt][kk] = *(const bf16x8*)(Vt + (dt * 2 + kk) * 512);

        // S^T = K * Q^T
        floatx4 sacc[4][4];
#pragma unroll
        for (int mt = 0; mt < 4; ++mt)
#pragma unroll
            for (int nt = 0; nt < 4; ++nt) { floatx4 z = {0.f, 0.f, 0.f, 0.f}; sacc[mt][nt] = z; }
#pragma unroll
        for (int kk = 0; kk < 2; ++kk)
#pragma unroll
            for (int mt = 0; mt < 4; ++mt)
#pragma unroll
                for (int nt = 0; nt < 4; ++nt)
                    sacc[mt][nt] = __builtin_amdgcn_mfma_f32_16x16x32_bf16(kf[mt][kk], qf[nt][kk], sacc[mt][nt], 0, 0, 0);

        // prefetch next iter's K frags
        int ktn = (it < 7) ? kt + 1 : kt0;
        const bf16_t* Kn = Kfh + (size_t)ktn * 8 * 512;
#pragma unroll
        for (int mt = 0; mt < 4; ++mt)
#pragma unroll
            for (int kk = 0; kk < 2; ++kk)
                kfn[mt][kk] = *(const bf16x8*)(Kn + (mt * 2 + kk) * 512);

        // exp2 + lsum + packed b64 P write (wave-private, swizzled)
#pragma unroll
        for (int mt = 0; mt < 4; ++mt)
#pragma unroll
            for (int nt = 0; nt < 4; ++nt) {
                float p0 = __builtin_amdgcn_exp2f(sacc[mt][nt][0]);
                float p1 = __builtin_amdgcn_exp2f(sacc[mt][nt][1]);
                float p2 = __builtin_amdgcn_exp2f(sacc[mt][nt][2]);
                float p3 = __builtin_amdgcn_exp2f(sacc[mt][nt][3]);
                lsum[nt] += (p0 + p1) + (p2 + p3);
                bf16x4 pk = {(bf16_t)p0, (bf16_t)p1, (bf16_t)p2, (bf16_t)p3};
                *(bf16x4*)&Ps[w * 4096 + (nt * 16 + lm) * 64 + (((mt * 4 + g) ^ xsw) << 2)] = pk;
            }

        // O^T += V^T * P^T
#pragma unroll
        for (int kk = 0; kk < 2; ++kk) {
            bf16x8 bp[4];
#pragma unroll
            for (int nt = 0; nt < 4; ++nt)
                bp[nt] = *(const bf16x8*)&Ps[w * 4096 + (nt * 16 + lm) * 64 + (((kk * 8 + g * 2) ^ xsw) << 2)];
#pragma unroll
            for (int dt = 0; dt < 4; ++dt)
#pragma unroll
                for (int nt = 0; nt < 4; ++nt)
                    oacc[dt][nt] = __builtin_amdgcn_mfma_f32_16x16x32_bf16(vf[dt][kk], bp[nt], oacc[dt][nt], 0, 0, 0);
        }

        // rotate K double-buffer
#pragma unroll
        for (int mt = 0; mt < 4; ++mt)
#pragma unroll
            for (int kk = 0; kk < 2; ++kk)
                kf[mt][kk] = kfn[mt][kk];
    }

    // reduce lsum within wave across g-groups
#pragma unroll
    for (int nt = 0; nt < 4; ++nt) {
        float s = lsum[nt];
        s += __shfl_xor(s, 16, 64);
        s += __shfl_xor(s, 32, 64);
        lsum[nt] = s;
    }

    // 4-partial merge through LDS (2 d-passes; every wave sums its q-quarter)
    float linv = 0.f;
#pragma unroll
    for (int p = 0; p < 2; ++p) {
        __syncthreads();
#pragma unroll
        for (int dh = 0; dh < 2; ++dh) {
            int dt = p * 2 + dh;
#pragma unroll
            for (int nt = 0; nt < 4; ++nt)
                *(floatx4*)&Mbuf[w * 2304 + (nt * 16 + lm) * 36 + dh * 16 + g * 4] = oacc[dt][nt];
        }
        if (p == 0 && g == 0)
#pragma unroll
            for (int nt = 0; nt < 4; ++nt)
                Lbuf[w * 64 + nt * 16 + lm] = lsum[nt];
        __syncthreads();
        if (p == 0) {
            float lt = 0.f;
#pragma unroll
            for (int w2 = 0; w2 < 4; ++w2)
                lt += Lbuf[w2 * 64 + w * 16 + lm];
            linv = 1.0f / lt;
        }
#pragma unroll
        for (int cc = 0; cc < 2; ++cc) {
            floatx4 s = {0.f, 0.f, 0.f, 0.f};
#pragma unroll
            for (int w2 = 0; w2 < 4; ++w2)
                s += *(const floatx4*)&Mbuf[w2 * 2304 + (w * 16 + lm) * 36 + cc * 16 + g * 4];
            bf16x4 pk = {(bf16_t)(s[0] * linv), (bf16_t)(s[1] * linv),
                         (bf16_t)(s[2] * linv), (bf16_t)(s[3] * linv)};
            int q = q0 + w * 16 + lm;
            int d = h * DKH + p * 32 + cc * 16 + g * 4;
            *(bf16x4*)&Cc[((size_t)(b * SEQ + q)) * DMODEL + d] = pk;
        }
    }
}

// ----------------------------------------------------------------------------
extern "C" void kernel_launch(void* const* d_in, const int* in_sizes, int n_in,
                              void* d_out, int out_size, void* d_ws, size_t ws_size,
                              hipStream_t stream) {
    const float* x  = (const float*)d_in[0];
    const float* Wq = (const float*)d_in[1];
    const float* Wk = (const float*)d_in[2];
    const float* Wv = (const float*)d_in[3];
    const float* Wo = (const float*)d_in[4];

    const size_t NX = (size_t)MROWS * DMODEL;
    const size_t NW = (size_t)DMODEL * DMODEL;
    bf16_t* ws  = (bf16_t*)d_ws;
    bf16_t* xb  = ws;            // x bf16
    bf16_t* Wt  = xb + NX;       // W^T x4 contiguous: q,k,v,o
    bf16_t* Wto = Wt + 3 * NW;
    bf16_t* Qb  = Wt + 4 * NW;   // Q (b,h,s,d), scaled log2(e)/8
    bf16_t* Kfb = Qb + NX;       // K frag-major
    bf16_t* Vfb = Kfb + NX;      // V frag-major
    bf16_t* Cc  = Vfb + NX;      // concat

    cast_x_kernel<<<NX / 1024, 256, 0, stream>>>(x, xb);
    transpose4_kernel<<<dim3(32, 32, 4), dim3(32, 8), 0, stream>>>(Wq, Wk, Wv, Wo, Wt);

    gemm128_kernel<0><<<dim3(3 * DMODEL / 128, MROWS / 128), 256, 0, stream>>>(xb, Wt, Qb);

    attn_kernel<<<dim3(BATCH * NHEADS, SEQ / 64), 256, 0, stream>>>(Qb, Kfb, Vfb, Cc);

    gemmO_kernel<<<dim3(DMODEL / 128, MROWS / 64), 256, 0, stream>>>(Cc, Wto, (float*)d_out);
}

// Round 8
// 177.653 us; speedup vs baseline: 2.5596x; 1.1000x over previous
//
#include <hip/hip_runtime.h>
#include <hip/hip_bf16.h>
#include <math.h>

#define DMODEL 1024
#define NHEADS 16
#define DKH    64
#define BATCH  2
#define SEQ    2048
#define MROWS  (BATCH * SEQ)   // 4096
#define LOG2E  1.4426950408889634f

typedef __bf16 bf16_t;
typedef bf16_t bf16x8 __attribute__((ext_vector_type(8)));
typedef bf16_t bf16x4 __attribute__((ext_vector_type(4)));
typedef float  floatx4 __attribute__((ext_vector_type(4)));

// async global->LDS, 16B per lane
__device__ __forceinline__ void glds16(const bf16_t* g, bf16_t* l) {
    __builtin_amdgcn_global_load_lds((__attribute__((address_space(1))) unsigned*)(g),
                                     (__attribute__((address_space(3))) unsigned*)(l),
                                     16, 0, 0);
}

// ---------------------------------------------------------------- prep: cast x (z=0) + transpose W (z=1..4)
__global__ void prep_kernel(const float* __restrict__ x,
                            const float* __restrict__ W0, const float* __restrict__ W1,
                            const float* __restrict__ W2, const float* __restrict__ W3,
                            bf16_t* __restrict__ xb, bf16_t* __restrict__ Wt) {
    __shared__ float t[32][33];
    int bx = blockIdx.x, by = blockIdx.y, z = blockIdx.z;
    int tx = threadIdx.x, ty = threadIdx.y;
    if (z == 0) {   // cast x: 128 rows x 32 cols per block
#pragma unroll
        for (int k = 0; k < 16; ++k) {
            int row = by * 128 + k * 8 + ty;
            int col = bx * 32 + tx;
            xb[(size_t)row * DMODEL + col] = (bf16_t)x[(size_t)row * DMODEL + col];
        }
        return;
    }
    const float* W = (z == 1) ? W0 : (z == 2) ? W1 : (z == 3) ? W2 : W3;
    bf16_t* dst = Wt + (size_t)(z - 1) * DMODEL * DMODEL;
#pragma unroll
    for (int i = 0; i < 32; i += 8)
        t[ty + i][tx] = W[(size_t)(by * 32 + ty + i) * DMODEL + bx * 32 + tx];
    __syncthreads();
#pragma unroll
    for (int i = 0; i < 32; i += 8)
        dst[(size_t)(bx * 32 + ty + i) * DMODEL + by * 32 + tx] = (bf16_t)t[tx][ty + i];
}

// ---------------------------------------------------------------- fused QKV GEMM, 128x128, BK=64
// Epilogue assembles outputs in the dead As/Bs LDS (32 KB), then streams 1KB-coalesced bursts.
// Q -> (b,h,s,d) scaled by log2(e)/8; K,V -> frag-major: ((bh*32+kt)*8+sub)*512 + lane*8 + j.
__global__ __launch_bounds__(256) void gemm_qkv_kernel(const bf16_t* __restrict__ A,
                                                       const bf16_t* __restrict__ Bt,
                                                       bf16_t* __restrict__ Qb,
                                                       bf16_t* __restrict__ Kfb,
                                                       bf16_t* __restrict__ Vfb) {
    __shared__ bf16_t sm[16384];
    bf16_t* As = sm;
    bf16_t* Bs = sm + 8192;
    int tid = threadIdx.x;
    int w = tid >> 6, l = tid & 63, g = l >> 4, lm = l & 15;
    int wr = w >> 1, wc = w & 1;
    int m0 = blockIdx.y * 128, n0 = blockIdx.x * 128;
    int r8 = l >> 3, s8 = l & 7, cw = s8 ^ r8;

    floatx4 acc[4][4];
#pragma unroll
    for (int i = 0; i < 4; ++i)
#pragma unroll
        for (int j = 0; j < 4; ++j) { floatx4 z = {0.f, 0.f, 0.f, 0.f}; acc[i][j] = z; }

    const bf16_t* Ag = A  + (size_t)(m0 + w * 32 + r8) * DMODEL + cw * 8;
    const bf16_t* Bg = Bt + (size_t)(n0 + w * 32 + r8) * DMODEL + cw * 8;

    for (int k0 = 0; k0 < DMODEL; k0 += 64) {
        __syncthreads();
#pragma unroll
        for (int j = 0; j < 4; ++j) {
            glds16(Ag + (size_t)j * 8 * DMODEL + k0, &As[(w * 32 + j * 8) * 64]);
            glds16(Bg + (size_t)j * 8 * DMODEL + k0, &Bs[(w * 32 + j * 8) * 64]);
        }
        __syncthreads();
#pragma unroll
        for (int kk = 0; kk < 2; ++kk) {
            bf16x8 af[4], bfr[4];
            int c = kk * 4 + g;
            int sw = (c ^ (lm & 7)) * 8;
#pragma unroll
            for (int i = 0; i < 4; ++i) {
                af[i]  = *(const bf16x8*)&As[(wr * 64 + i * 16 + lm) * 64 + sw];
                bfr[i] = *(const bf16x8*)&Bs[(wc * 64 + i * 16 + lm) * 64 + sw];
            }
#pragma unroll
            for (int i = 0; i < 4; ++i)
#pragma unroll
                for (int j = 0; j < 4; ++j)
                    acc[i][j] = __builtin_amdgcn_mfma_f32_16x16x32_bf16(af[i], bfr[j], acc[i][j], 0, 0, 0);
        }
    }

    __syncthreads();   // As/Bs frag reads done; reuse sm as epilogue buffer
    int mat = n0 >> 10;                 // block-uniform: 0=Q, 1=K, 2=V
    int headb = (n0 & 1023) >> 6;       // first head covered by this block
    int b = m0 >> 11;
    if (mat == 0) {
        // LDS: chunk hl(=wc)*8192 + s_in_block*64 + d   (two 16 KB (s,d)-contiguous chunks)
#pragma unroll
        for (int i = 0; i < 4; ++i)
#pragma unroll
            for (int j = 0; j < 4; ++j) {
                int d = j * 16 + lm;
                int so = wr * 64 + i * 16 + g * 4;
#pragma unroll
                for (int r = 0; r < 4; ++r)
                    sm[wc * 8192 + (so + r) * 64 + d] = (bf16_t)(acc[i][j][r] * (0.125f * LOG2E));
            }
        __syncthreads();
        int sbase = m0 & 2047;
#pragma unroll
        for (int rep = 0; rep < 8; ++rep) {
            int idx = rep * 256 + tid;          // 2048 vec8 slots
            int c = idx >> 10;                  // chunk (head)
            int off = (idx & 1023) * 8;
            bf16_t* dst = Qb + ((size_t)(b * NHEADS + headb + c) * SEQ + sbase) * DKH + off;
            *(bf16x8*)dst = *(const bf16x8*)&sm[c * 8192 + off];
        }
    } else if (mat == 1) {
        // K frag-major: chunk c = hl*2+ktl (=wc*2+wr), 4 x 4096-elem chunks
#pragma unroll
        for (int i = 0; i < 4; ++i)
#pragma unroll
            for (int j = 0; j < 4; ++j) {
                int d = j * 16 + lm;
                int base = (wc * 2 + wr) * 4096 + (i * 2 + (d >> 5)) * 512 + ((d >> 3) & 3) * 128 + (d & 7);
#pragma unroll
                for (int r = 0; r < 4; ++r)
                    sm[base + (g * 4 + r) * 8] = (bf16_t)acc[i][j][r];
            }
        __syncthreads();
        int ktb = (m0 & 2047) >> 6;
#pragma unroll
        for (int rep = 0; rep < 8; ++rep) {
            int idx = rep * 256 + tid;
            int c = idx >> 9;                   // 512 vec8 per 4096-elem chunk
            int off = (idx & 511) * 8;
            int bh2 = b * NHEADS + headb + (c >> 1);
            int kt = ktb + (c & 1);
            *(bf16x8*)(Kfb + ((size_t)bh2 * 32 + kt) * 4096 + off) = *(const bf16x8*)&sm[c * 4096 + off];
        }
    } else {
        // V frag-major (from V^T view): dt=j, lmV=lm, kkV=i>>1, gV=(i&1)*2+(g>>1), jV=(g&1)*4+r
#pragma unroll
        for (int i = 0; i < 4; ++i)
#pragma unroll
            for (int j = 0; j < 4; ++j) {
                int base = (wc * 2 + wr) * 4096 + (j * 2 + (i >> 1)) * 512 +
                           (((i & 1) * 2 + (g >> 1)) * 16 + lm) * 8 + (g & 1) * 4;
                bf16x4 pk = {(bf16_t)acc[i][j][0], (bf16_t)acc[i][j][1],
                             (bf16_t)acc[i][j][2], (bf16_t)acc[i][j][3]};
                *(bf16x4*)&sm[base] = pk;
            }
        __syncthreads();
        int ktb = (m0 & 2047) >> 6;
#pragma unroll
        for (int rep = 0; rep < 8; ++rep) {
            int idx = rep * 256 + tid;
            int c = idx >> 9;
            int off = (idx & 511) * 8;
            int bh2 = b * NHEADS + headb + (c >> 1);
            int kt = ktb + (c & 1);
            *(bf16x8*)(Vfb + ((size_t)bh2 * 32 + kt) * 4096 + off) = *(const bf16x8*)&sm[c * 4096 + off];
        }
    }
}

// ---------------------------------------------------------------- O-proj GEMM, 64x128 tile
__global__ __launch_bounds__(256) void gemmO_kernel(const bf16_t* __restrict__ A,
                                                    const bf16_t* __restrict__ Bt,
                                                    float* __restrict__ outp) {
    __shared__ bf16_t As[64 * 64];
    __shared__ bf16_t Bs[128 * 64];
    int tid = threadIdx.x;
    int w = tid >> 6, l = tid & 63, g = l >> 4, lm = l & 15;
    int wr = w & 1, wc = w >> 1;
    int m0 = blockIdx.y * 64, n0 = blockIdx.x * 128;
    int r8 = l >> 3, s8 = l & 7, cw = s8 ^ r8;

    floatx4 acc[2][4];
#pragma unroll
    for (int i = 0; i < 2; ++i)
#pragma unroll
        for (int j = 0; j < 4; ++j) { floatx4 z = {0.f, 0.f, 0.f, 0.f}; acc[i][j] = z; }

    const bf16_t* Ag = A  + (size_t)(m0 + w * 16 + r8) * DMODEL + cw * 8;
    const bf16_t* Bg = Bt + (size_t)(n0 + w * 32 + r8) * DMODEL + cw * 8;

    for (int k0 = 0; k0 < DMODEL; k0 += 64) {
        __syncthreads();
#pragma unroll
        for (int j = 0; j < 2; ++j)
            glds16(Ag + (size_t)j * 8 * DMODEL + k0, &As[(w * 16 + j * 8) * 64]);
#pragma unroll
        for (int j = 0; j < 4; ++j)
            glds16(Bg + (size_t)j * 8 * DMODEL + k0, &Bs[(w * 32 + j * 8) * 64]);
        __syncthreads();
#pragma unroll
        for (int kk = 0; kk < 2; ++kk) {
            bf16x8 af[2], bfr[4];
            int c = kk * 4 + g;
            int sw = (c ^ (lm & 7)) * 8;
#pragma unroll
            for (int i = 0; i < 2; ++i)
                af[i] = *(const bf16x8*)&As[(wr * 32 + i * 16 + lm) * 64 + sw];
#pragma unroll
            for (int j = 0; j < 4; ++j)
                bfr[j] = *(const bf16x8*)&Bs[(wc * 64 + j * 16 + lm) * 64 + sw];
#pragma unroll
            for (int i = 0; i < 2; ++i)
#pragma unroll
                for (int j = 0; j < 4; ++j)
                    acc[i][j] = __builtin_amdgcn_mfma_f32_16x16x32_bf16(af[i], bfr[j], acc[i][j], 0, 0, 0);
        }
    }

#pragma unroll
    for (int i = 0; i < 2; ++i)
#pragma unroll
        for (int j = 0; j < 4; ++j) {
            int nc = n0 + wc * 64 + j * 16 + lm;
            int mb = m0 + wr * 32 + i * 16 + g * 4;
#pragma unroll
            for (int r = 0; r < 4; ++r)
                outp[(size_t)(mb + r) * DMODEL + nc] = acc[i][j][r];
        }
}

// ---------------------------------------------------------------- fused flash attention
// grid (32 bh, 32 qblk), block 256 = 4 waves = 4-way key split over the same 64 q rows.
// Half-tile (32-key) software pipeline: loads(V0,K1) -> S0 -> loads(V1,K0') -> S1 ->
// exp0/P0/PV0 -> exp1/P1/PV1.  S(h+1) independent of exp(h) (double-buffered sacc).
// Cc stores assembled in LDS -> 16B/lane row bursts (fixes 10x write amplification).
// DO NOT use (256,4): compiler caps VGPR at 64 and spills ~1.5 GB/launch (R6: 320 us).
__global__ __launch_bounds__(256, 2) void attn_kernel(const bf16_t* __restrict__ Q,
                                                      const bf16_t* __restrict__ Kf,
                                                      const bf16_t* __restrict__ Vf,
                                                      bf16_t* __restrict__ Cc) {
    __shared__ __align__(16) char smem[41984];
    bf16_t* Ps   = (bf16_t*)smem;            // loop: [w][2048] half-P tiles
    float*  Mbuf = (float*)smem;             // merge: [w][64*36] (aliased after loop)
    float*  Lbuf = (float*)(smem + 36864);   // [w][64]
    bf16_t* Ct   = (bf16_t*)(smem + 37888);  // [w][512] store-assembly

    int tid = threadIdx.x;
    int w = tid >> 6, l = tid & 63, g = l >> 4, lm = l & 15;
    int bh = blockIdx.x, b = bh >> 4, h = bh & 15;
    int q0 = blockIdx.y * 64;
    int sw = lm & 6;          // write-chunk xor key (even -> b128 reads stay ordered)
    int s1 = sw >> 1;         // read-block xor key

    const bf16_t* Qh  = Q  + ((size_t)bh * SEQ + q0) * DKH;
    const bf16_t* Kfh = Kf + (size_t)bh * 32 * 4096 + l * 8;
    const bf16_t* Vfh = Vf + (size_t)bh * 32 * 4096 + l * 8;

    bf16x8 qf[4][2];
#pragma unroll
    for (int nt = 0; nt < 4; ++nt)
#pragma unroll
        for (int kk = 0; kk < 2; ++kk)
            qf[nt][kk] = *(const bf16x8*)(Qh + (size_t)(nt * 16 + lm) * DKH + kk * 32 + g * 8);

    floatx4 oacc[4][4];
#pragma unroll
    for (int dt = 0; dt < 4; ++dt)
#pragma unroll
        for (int nt = 0; nt < 4; ++nt) { floatx4 z = {0.f, 0.f, 0.f, 0.f}; oacc[dt][nt] = z; }
    float lsum[4] = {0.f, 0.f, 0.f, 0.f};

    int kt0 = w * 8;
    bf16x8 kfa[2][2], kfb[2][2], vfa[4], vfb[4];
    {
        const bf16_t* Kb0 = Kfh + (size_t)kt0 * 4096;
#pragma unroll
        for (int m2 = 0; m2 < 2; ++m2)
#pragma unroll
            for (int kk = 0; kk < 2; ++kk)
                kfa[m2][kk] = *(const bf16x8*)(Kb0 + (m2 * 2 + kk) * 512);
    }

    for (int it = 0; it < 8; ++it) {
        const bf16_t* Tb = Kfh + (size_t)(kt0 + it) * 4096;
        const bf16_t* Vb = Vfh + (size_t)(kt0 + it) * 4096;
        const bf16_t* Tn = Kfh + (size_t)(kt0 + ((it < 7) ? it + 1 : 0)) * 4096;

        // loads: V half0, K half1
#pragma unroll
        for (int dt = 0; dt < 4; ++dt) vfa[dt] = *(const bf16x8*)(Vb + (dt * 2 + 0) * 512);
#pragma unroll
        for (int m2 = 0; m2 < 2; ++m2)
#pragma unroll
            for (int kk = 0; kk < 2; ++kk)
                kfb[m2][kk] = *(const bf16x8*)(Tb + (4 + m2 * 2 + kk) * 512);

        // S half0 (keys 0..31 of tile)
        floatx4 sa[2][4];
#pragma unroll
        for (int m2 = 0; m2 < 2; ++m2)
#pragma unroll
            for (int nt = 0; nt < 4; ++nt) { floatx4 z = {0.f, 0.f, 0.f, 0.f}; sa[m2][nt] = z; }
#pragma unroll
        for (int kk = 0; kk < 2; ++kk)
#pragma unroll
            for (int m2 = 0; m2 < 2; ++m2)
#pragma unroll
                for (int nt = 0; nt < 4; ++nt)
                    sa[m2][nt] = __builtin_amdgcn_mfma_f32_16x16x32_bf16(kfa[m2][kk], qf[nt][kk], sa[m2][nt], 0, 0, 0);

        // loads: V half1, K half0 of next tile
#pragma unroll
        for (int dt = 0; dt < 4; ++dt) vfb[dt] = *(const bf16x8*)(Vb + (dt * 2 + 1) * 512);
#pragma unroll
        for (int m2 = 0; m2 < 2; ++m2)
#pragma unroll
            for (int kk = 0; kk < 2; ++kk)
                kfa[m2][kk] = *(const bf16x8*)(Tn + (m2 * 2 + kk) * 512);

        // S half1 (keys 32..63) — independent of exp(half0)
        floatx4 sb[2][4];
#pragma unroll
        for (int m2 = 0; m2 < 2; ++m2)
#pragma unroll
            for (int nt = 0; nt < 4; ++nt) { floatx4 z = {0.f, 0.f, 0.f, 0.f}; sb[m2][nt] = z; }
#pragma unroll
        for (int kk = 0; kk < 2; ++kk)
#pragma unroll
            for (int m2 = 0; m2 < 2; ++m2)
#pragma unroll
                for (int nt = 0; nt < 4; ++nt)
                    sb[m2][nt] = __builtin_amdgcn_mfma_f32_16x16x32_bf16(kfb[m2][kk], qf[nt][kk], sb[m2][nt], 0, 0, 0);

        // --- half0: exp + P write + PV ---
#pragma unroll
        for (int m2 = 0; m2 < 2; ++m2)
#pragma unroll
            for (int nt = 0; nt < 4; ++nt) {
                float p0 = __builtin_amdgcn_exp2f(sa[m2][nt][0]);
                float p1 = __builtin_amdgcn_exp2f(sa[m2][nt][1]);
                float p2 = __builtin_amdgcn_exp2f(sa[m2][nt][2]);
                float p3 = __builtin_amdgcn_exp2f(sa[m2][nt][3]);
                lsum[nt] += (p0 + p1) + (p2 + p3);
                bf16x4 pk = {(bf16_t)p0, (bf16_t)p1, (bf16_t)p2, (bf16_t)p3};
                *(bf16x4*)&Ps[w * 2048 + (nt * 16 + lm) * 32 + (((m2 * 4 + g) ^ sw) << 2)] = pk;
            }
        {
            bf16x8 bp[4];
#pragma unroll
            for (int nt = 0; nt < 4; ++nt)
                bp[nt] = *(const bf16x8*)&Ps[w * 2048 + (nt * 16 + lm) * 32 + ((g ^ s1) << 3)];
#pragma unroll
            for (int dt = 0; dt < 4; ++dt)
#pragma unroll
                for (int nt = 0; nt < 4; ++nt)
                    oacc[dt][nt] = __builtin_amdgcn_mfma_f32_16x16x32_bf16(vfa[dt], bp[nt], oacc[dt][nt], 0, 0, 0);
        }

        // --- half1: exp + P write + PV ---
#pragma unroll
        for (int m2 = 0; m2 < 2; ++m2)
#pragma unroll
            for (int nt = 0; nt < 4; ++nt) {
                float p0 = __builtin_amdgcn_exp2f(sb[m2][nt][0]);
                float p1 = __builtin_amdgcn_exp2f(sb[m2][nt][1]);
                float p2 = __builtin_amdgcn_exp2f(sb[m2][nt][2]);
                float p3 = __builtin_amdgcn_exp2f(sb[m2][nt][3]);
                lsum[nt] += (p0 + p1) + (p2 + p3);
                bf16x4 pk = {(bf16_t)p0, (bf16_t)p1, (bf16_t)p2, (bf16_t)p3};
                *(bf16x4*)&Ps[w * 2048 + (nt * 16 + lm) * 32 + (((m2 * 4 + g) ^ sw) << 2)] = pk;
            }
        {
            bf16x8 bp[4];
#pragma unroll
            for (int nt = 0; nt < 4; ++nt)
                bp[nt] = *(const bf16x8*)&Ps[w * 2048 + (nt * 16 + lm) * 32 + ((g ^ s1) << 3)];
#pragma unroll
            for (int dt = 0; dt < 4; ++dt)
#pragma unroll
                for (int nt = 0; nt < 4; ++nt)
                    oacc[dt][nt] = __builtin_amdgcn_mfma_f32_16x16x32_bf16(vfb[dt], bp[nt], oacc[dt][nt], 0, 0, 0);
        }
    }

    // reduce lsum within wave across g-groups
#pragma unroll
    for (int nt = 0; nt < 4; ++nt) {
        float s = lsum[nt];
        s += __shfl_xor(s, 16, 64);
        s += __shfl_xor(s, 32, 64);
        lsum[nt] = s;
    }

    // 4-partial merge through LDS; coalesced Cc stores via Ct
    float linv = 0.f;
#pragma unroll
    for (int p = 0; p < 2; ++p) {
        __syncthreads();
#pragma unroll
        for (int dh = 0; dh < 2; ++dh) {
            int dt = p * 2 + dh;
#pragma unroll
            for (int nt = 0; nt < 4; ++nt)
                *(floatx4*)&Mbuf[w * 2304 + (nt * 16 + lm) * 36 + dh * 16 + g * 4] = oacc[dt][nt];
        }
        if (p == 0 && g == 0)
#pragma unroll
            for (int nt = 0; nt < 4; ++nt)
                Lbuf[w * 64 + nt * 16 + lm] = lsum[nt];
        __syncthreads();
        if (p == 0) {
            float lt = 0.f;
#pragma unroll
            for (int w2 = 0; w2 < 4; ++w2)
                lt += Lbuf[w2 * 64 + w * 16 + lm];
            linv = 1.0f / lt;
        }
#pragma unroll
        for (int cc = 0; cc < 2; ++cc) {
            floatx4 s = {0.f, 0.f, 0.f, 0.f};
#pragma unroll
            for (int w2 = 0; w2 < 4; ++w2)
                s += *(const floatx4*)&Mbuf[w2 * 2304 + (w * 16 + lm) * 36 + cc * 16 + g * 4];
            bf16x4 pk = {(bf16_t)(s[0] * linv), (bf16_t)(s[1] * linv),
                         (bf16_t)(s[2] * linv), (bf16_t)(s[3] * linv)};
            *(bf16x4*)&Ct[w * 512 + lm * 32 + cc * 16 + g * 4] = pk;
        }
        // cooperative row store: lane = (row, dpart); 16B/lane, 64B full sectors
        {
            int row = l >> 2, dp = l & 3;
            bf16x8 v = *(const bf16x8*)&Ct[w * 512 + row * 32 + dp * 8];
            *(bf16x8*)&Cc[((size_t)(b * SEQ + q0 + w * 16 + row)) * DMODEL + h * DKH + p * 32 + dp * 8] = v;
        }
    }
}

// ----------------------------------------------------------------------------
extern "C" void kernel_launch(void* const* d_in, const int* in_sizes, int n_in,
                              void* d_out, int out_size, void* d_ws, size_t ws_size,
                              hipStream_t stream) {
    const float* x  = (const float*)d_in[0];
    const float* Wq = (const float*)d_in[1];
    const float* Wk = (const float*)d_in[2];
    const float* Wv = (const float*)d_in[3];
    const float* Wo = (const float*)d_in[4];

    const size_t NX = (size_t)MROWS * DMODEL;
    const size_t NW = (size_t)DMODEL * DMODEL;
    bf16_t* ws  = (bf16_t*)d_ws;
    bf16_t* xb  = ws;            // x bf16
    bf16_t* Wt  = xb + NX;       // W^T x4 contiguous: q,k,v,o
    bf16_t* Wto = Wt + 3 * NW;
    bf16_t* Qb  = Wt + 4 * NW;   // Q (b,h,s,d), scaled log2(e)/8
    bf16_t* Kfb = Qb + NX;       // K frag-major
    bf16_t* Vfb = Kfb + NX;      // V frag-major
    bf16_t* Cc  = Vfb + NX;      // concat

    prep_kernel<<<dim3(32, 32, 5), dim3(32, 8), 0, stream>>>(x, Wq, Wk, Wv, Wo, xb, Wt);

    gemm_qkv_kernel<<<dim3(3 * DMODEL / 128, MROWS / 128), 256, 0, stream>>>(xb, Wt, Qb, Kfb, Vfb);

    attn_kernel<<<dim3(BATCH * NHEADS, SEQ / 64), 256, 0, stream>>>(Qb, Kfb, Vfb, Cc);

    gemmO_kernel<<<dim3(DMODEL / 128, MROWS / 64), 256, 0, stream>>>(Cc, Wto, (float*)d_out);
}

// Round 9
// 175.704 us; speedup vs baseline: 2.5880x; 1.0111x over previous
//
#include <hip/hip_runtime.h>
#include <hip/hip_bf16.h>
#include <math.h>

#define DMODEL 1024
#define NHEADS 16
#define DKH    64
#define BATCH  2
#define SEQ    2048
#define MROWS  (BATCH * SEQ)   // 4096
#define LOG2E  1.4426950408889634f

typedef __bf16 bf16_t;
typedef bf16_t bf16x8 __attribute__((ext_vector_type(8)));
typedef bf16_t bf16x4 __attribute__((ext_vector_type(4)));
typedef float  floatx4 __attribute__((ext_vector_type(4)));

// async global->LDS, 16B per lane
__device__ __forceinline__ void glds16(const bf16_t* g, bf16_t* l) {
    __builtin_amdgcn_global_load_lds((__attribute__((address_space(1))) unsigned*)(g),
                                     (__attribute__((address_space(3))) unsigned*)(l),
                                     16, 0, 0);
}

// ---------------------------------------------------------------- prep: cast x (z=0) + transpose W (z=1..4)
__global__ void prep_kernel(const float* __restrict__ x,
                            const float* __restrict__ W0, const float* __restrict__ W1,
                            const float* __restrict__ W2, const float* __restrict__ W3,
                            bf16_t* __restrict__ xb, bf16_t* __restrict__ Wt) {
    __shared__ float t[32][33];
    int bx = blockIdx.x, by = blockIdx.y, z = blockIdx.z;
    int tx = threadIdx.x, ty = threadIdx.y;
    if (z == 0) {   // cast x: 128 rows x 32 cols per block, float4-vectorized
        int tid = ty * 32 + tx;
#pragma unroll
        for (int k = 0; k < 4; ++k) {
            int slot = k * 256 + tid;            // 0..1023 float4 slots
            int row = by * 128 + (slot >> 3);
            int col = bx * 32 + (slot & 7) * 4;
            float4 v = *(const float4*)&x[(size_t)row * DMODEL + col];
            bf16x4 o = {(bf16_t)v.x, (bf16_t)v.y, (bf16_t)v.z, (bf16_t)v.w};
            *(bf16x4*)&xb[(size_t)row * DMODEL + col] = o;
        }
        return;
    }
    const float* W = (z == 1) ? W0 : (z == 2) ? W1 : (z == 3) ? W2 : W3;
    bf16_t* dst = Wt + (size_t)(z - 1) * DMODEL * DMODEL;
#pragma unroll
    for (int i = 0; i < 32; i += 8)
        t[ty + i][tx] = W[(size_t)(by * 32 + ty + i) * DMODEL + bx * 32 + tx];
    __syncthreads();
#pragma unroll
    for (int i = 0; i < 32; i += 8)
        dst[(size_t)(bx * 32 + ty + i) * DMODEL + by * 32 + tx] = (bf16_t)t[tx][ty + i];
}

// ---------------------------------------------------------------- fused QKV GEMM, 128x128, BK=64
// Epilogue assembles outputs in the dead As/Bs LDS, then streams 1KB-coalesced bursts.
// ALL THREE outputs frag-major: ((bh*32 + tile)*8 + sub)*512 + lane*8 + j
//   Q (as B-operand frags, scaled log2(e)/8) and K (A-operand frags): identical
//   transform — lane maps A[m][k]/B[k][n] are the same formula (lane&15, lane>>4).
//   V from the V^T view.
__global__ __launch_bounds__(256) void gemm_qkv_kernel(const bf16_t* __restrict__ A,
                                                       const bf16_t* __restrict__ Bt,
                                                       bf16_t* __restrict__ Qfb,
                                                       bf16_t* __restrict__ Kfb,
                                                       bf16_t* __restrict__ Vfb) {
    __shared__ bf16_t sm[16384];
    bf16_t* As = sm;
    bf16_t* Bs = sm + 8192;
    int tid = threadIdx.x;
    int w = tid >> 6, l = tid & 63, g = l >> 4, lm = l & 15;
    int wr = w >> 1, wc = w & 1;
    int m0 = blockIdx.y * 128, n0 = blockIdx.x * 128;
    int r8 = l >> 3, s8 = l & 7, cw = s8 ^ r8;

    floatx4 acc[4][4];
#pragma unroll
    for (int i = 0; i < 4; ++i)
#pragma unroll
        for (int j = 0; j < 4; ++j) { floatx4 z = {0.f, 0.f, 0.f, 0.f}; acc[i][j] = z; }

    const bf16_t* Ag = A  + (size_t)(m0 + w * 32 + r8) * DMODEL + cw * 8;
    const bf16_t* Bg = Bt + (size_t)(n0 + w * 32 + r8) * DMODEL + cw * 8;

    for (int k0 = 0; k0 < DMODEL; k0 += 64) {
        __syncthreads();
#pragma unroll
        for (int j = 0; j < 4; ++j) {
            glds16(Ag + (size_t)j * 8 * DMODEL + k0, &As[(w * 32 + j * 8) * 64]);
            glds16(Bg + (size_t)j * 8 * DMODEL + k0, &Bs[(w * 32 + j * 8) * 64]);
        }
        __syncthreads();
#pragma unroll
        for (int kk = 0; kk < 2; ++kk) {
            bf16x8 af[4], bfr[4];
            int c = kk * 4 + g;
            int sw = (c ^ (lm & 7)) * 8;
#pragma unroll
            for (int i = 0; i < 4; ++i) {
                af[i]  = *(const bf16x8*)&As[(wr * 64 + i * 16 + lm) * 64 + sw];
                bfr[i] = *(const bf16x8*)&Bs[(wc * 64 + i * 16 + lm) * 64 + sw];
            }
#pragma unroll
            for (int i = 0; i < 4; ++i)
#pragma unroll
                for (int j = 0; j < 4; ++j)
                    acc[i][j] = __builtin_amdgcn_mfma_f32_16x16x32_bf16(af[i], bfr[j], acc[i][j], 0, 0, 0);
        }
    }

    __syncthreads();   // As/Bs frag reads done; reuse sm as epilogue buffer
    int mat = n0 >> 10;                 // block-uniform: 0=Q, 1=K, 2=V
    int headb = (n0 & 1023) >> 6;
    int b = m0 >> 11;
    int ktb = (m0 & 2047) >> 6;         // s-tile base (q-tile for Q, key-tile for K/V)
    float scale = (mat == 0) ? (0.125f * LOG2E) : 1.0f;

    if (mat <= 1) {
        // Q/K frag-major: chunk c = wc*2+wr; sub = mt*2+kk (mt from s, kk from d);
        // elem = (gd*16 + (s&15))*8 + (d&7)
#pragma unroll
        for (int i = 0; i < 4; ++i)
#pragma unroll
            for (int j = 0; j < 4; ++j) {
                int d = j * 16 + lm;
                int base = (wc * 2 + wr) * 4096 + (i * 2 + (d >> 5)) * 512 + ((d >> 3) & 3) * 128 + (d & 7);
#pragma unroll
                for (int r = 0; r < 4; ++r)
                    sm[base + (g * 4 + r) * 8] = (bf16_t)(acc[i][j][r] * scale);
            }
    } else {
        // V frag-major (from V^T view): sub = dt*2+kkV (from d and s)
#pragma unroll
        for (int i = 0; i < 4; ++i)
#pragma unroll
            for (int j = 0; j < 4; ++j) {
                int base = (wc * 2 + wr) * 4096 + (j * 2 + (i >> 1)) * 512 +
                           (((i & 1) * 2 + (g >> 1)) * 16 + lm) * 8 + (g & 1) * 4;
                bf16x4 pk = {(bf16_t)acc[i][j][0], (bf16_t)acc[i][j][1],
                             (bf16_t)acc[i][j][2], (bf16_t)acc[i][j][3]};
                *(bf16x4*)&sm[base] = pk;
            }
    }
    __syncthreads();
    bf16_t* outbuf = (mat == 0) ? Qfb : (mat == 1) ? Kfb : Vfb;
#pragma unroll
    for (int rep = 0; rep < 8; ++rep) {
        int idx = rep * 256 + tid;
        int c = idx >> 9;                   // 512 vec8 per 4096-elem chunk
        int off = (idx & 511) * 8;
        int bh2 = b * NHEADS + headb + (c >> 1);
        int kt = ktb + (c & 1);
        *(bf16x8*)(outbuf + ((size_t)bh2 * 32 + kt) * 4096 + off) = *(const bf16x8*)&sm[c * 4096 + off];
    }
}

// ---------------------------------------------------------------- O-proj GEMM, 64x128 tile
__global__ __launch_bounds__(256) void gemmO_kernel(const bf16_t* __restrict__ A,
                                                    const bf16_t* __restrict__ Bt,
                                                    float* __restrict__ outp) {
    __shared__ bf16_t As[64 * 64];
    __shared__ bf16_t Bs[128 * 64];
    int tid = threadIdx.x;
    int w = tid >> 6, l = tid & 63, g = l >> 4, lm = l & 15;
    int wr = w & 1, wc = w >> 1;
    int m0 = blockIdx.y * 64, n0 = blockIdx.x * 128;
    int r8 = l >> 3, s8 = l & 7, cw = s8 ^ r8;

    floatx4 acc[2][4];
#pragma unroll
    for (int i = 0; i < 2; ++i)
#pragma unroll
        for (int j = 0; j < 4; ++j) { floatx4 z = {0.f, 0.f, 0.f, 0.f}; acc[i][j] = z; }

    const bf16_t* Ag = A  + (size_t)(m0 + w * 16 + r8) * DMODEL + cw * 8;
    const bf16_t* Bg = Bt + (size_t)(n0 + w * 32 + r8) * DMODEL + cw * 8;

    for (int k0 = 0; k0 < DMODEL; k0 += 64) {
        __syncthreads();
#pragma unroll
        for (int j = 0; j < 2; ++j)
            glds16(Ag + (size_t)j * 8 * DMODEL + k0, &As[(w * 16 + j * 8) * 64]);
#pragma unroll
        for (int j = 0; j < 4; ++j)
            glds16(Bg + (size_t)j * 8 * DMODEL + k0, &Bs[(w * 32 + j * 8) * 64]);
        __syncthreads();
#pragma unroll
        for (int kk = 0; kk < 2; ++kk) {
            bf16x8 af[2], bfr[4];
            int c = kk * 4 + g;
            int sw = (c ^ (lm & 7)) * 8;
#pragma unroll
            for (int i = 0; i < 2; ++i)
                af[i] = *(const bf16x8*)&As[(wr * 32 + i * 16 + lm) * 64 + sw];
#pragma unroll
            for (int j = 0; j < 4; ++j)
                bfr[j] = *(const bf16x8*)&Bs[(wc * 64 + j * 16 + lm) * 64 + sw];
#pragma unroll
            for (int i = 0; i < 2; ++i)
#pragma unroll
                for (int j = 0; j < 4; ++j)
                    acc[i][j] = __builtin_amdgcn_mfma_f32_16x16x32_bf16(af[i], bfr[j], acc[i][j], 0, 0, 0);
        }
    }

#pragma unroll
    for (int i = 0; i < 2; ++i)
#pragma unroll
        for (int j = 0; j < 4; ++j) {
            int nc = n0 + wc * 64 + j * 16 + lm;
            int mb = m0 + wr * 32 + i * 16 + g * 4;
#pragma unroll
            for (int r = 0; r < 4; ++r)
                outp[(size_t)(mb + r) * DMODEL + nc] = acc[i][j][r];
        }
}

// ---------------------------------------------------------------- fused flash attention
// grid (32 bh, 32 qblk), block 256 = 4 waves = 4-way key split over the same 64 q rows.
// Half-tile (32-key) software pipeline. Q/K/V all frag-major (every load = lane*16B,
// fully coalesced). P tile rows padded to 40 elems (80 B) -> <=2-way banks, no XOR.
// Ct rows 40 elems (fixes 8-way write conflict of stride-32).
// DO NOT use (256,4): compiler caps VGPR at 64 and spills ~1.5 GB/launch (R6: 320 us).
__global__ __launch_bounds__(256, 2) void attn_kernel(const bf16_t* __restrict__ Qf,
                                                      const bf16_t* __restrict__ Kf,
                                                      const bf16_t* __restrict__ Vf,
                                                      bf16_t* __restrict__ Cc) {
    __shared__ __align__(16) char smem[43008];
    bf16_t* Ps   = (bf16_t*)smem;            // loop: [w][64*40] half-P tiles (aliased under Mbuf)
    float*  Mbuf = (float*)smem;             // merge: [w][64*36]
    float*  Lbuf = (float*)(smem + 36864);   // [w][64]
    bf16_t* Ct   = (bf16_t*)(smem + 37888);  // [w][16*40] store-assembly

    int tid = threadIdx.x;
    int w = tid >> 6, l = tid & 63, g = l >> 4, lm = l & 15;
    int bh = blockIdx.x, b = bh >> 4, h = bh & 15;
    int q0 = blockIdx.y * 64;

    const bf16_t* Qfh = Qf + ((size_t)bh * 32 + (q0 >> 6)) * 4096 + l * 8;
    const bf16_t* Kfh = Kf + (size_t)bh * 32 * 4096 + l * 8;
    const bf16_t* Vfh = Vf + (size_t)bh * 32 * 4096 + l * 8;

    // Q B-frags: frag-major, 8 coalesced 1KB loads
    bf16x8 qf[4][2];
#pragma unroll
    for (int nt = 0; nt < 4; ++nt)
#pragma unroll
        for (int kk = 0; kk < 2; ++kk)
            qf[nt][kk] = *(const bf16x8*)(Qfh + (nt * 2 + kk) * 512);

    floatx4 oacc[4][4];
#pragma unroll
    for (int dt = 0; dt < 4; ++dt)
#pragma unroll
        for (int nt = 0; nt < 4; ++nt) { floatx4 z = {0.f, 0.f, 0.f, 0.f}; oacc[dt][nt] = z; }
    float lsum[4] = {0.f, 0.f, 0.f, 0.f};

    int kt0 = w * 8;
    bf16x8 kfa[2][2], kfb[2][2], vfa[4], vfb[4];
    {
        const bf16_t* Kb0 = Kfh + (size_t)kt0 * 4096;
#pragma unroll
        for (int m2 = 0; m2 < 2; ++m2)
#pragma unroll
            for (int kk = 0; kk < 2; ++kk)
                kfa[m2][kk] = *(const bf16x8*)(Kb0 + (m2 * 2 + kk) * 512);
    }

    for (int it = 0; it < 8; ++it) {
        const bf16_t* Tb = Kfh + (size_t)(kt0 + it) * 4096;
        const bf16_t* Vb = Vfh + (size_t)(kt0 + it) * 4096;
        const bf16_t* Tn = Kfh + (size_t)(kt0 + ((it < 7) ? it + 1 : 0)) * 4096;

        // loads: V half0, K half1
#pragma unroll
        for (int dt = 0; dt < 4; ++dt) vfa[dt] = *(const bf16x8*)(Vb + (dt * 2 + 0) * 512);
#pragma unroll
        for (int m2 = 0; m2 < 2; ++m2)
#pragma unroll
            for (int kk = 0; kk < 2; ++kk)
                kfb[m2][kk] = *(const bf16x8*)(Tb + (4 + m2 * 2 + kk) * 512);

        // S half0
        floatx4 sa[2][4];
#pragma unroll
        for (int m2 = 0; m2 < 2; ++m2)
#pragma unroll
            for (int nt = 0; nt < 4; ++nt) { floatx4 z = {0.f, 0.f, 0.f, 0.f}; sa[m2][nt] = z; }
#pragma unroll
        for (int kk = 0; kk < 2; ++kk)
#pragma unroll
            for (int m2 = 0; m2 < 2; ++m2)
#pragma unroll
                for (int nt = 0; nt < 4; ++nt)
                    sa[m2][nt] = __builtin_amdgcn_mfma_f32_16x16x32_bf16(kfa[m2][kk], qf[nt][kk], sa[m2][nt], 0, 0, 0);

        // loads: V half1, K half0 of next tile
#pragma unroll
        for (int dt = 0; dt < 4; ++dt) vfb[dt] = *(const bf16x8*)(Vb + (dt * 2 + 1) * 512);
#pragma unroll
        for (int m2 = 0; m2 < 2; ++m2)
#pragma unroll
            for (int kk = 0; kk < 2; ++kk)
                kfa[m2][kk] = *(const bf16x8*)(Tn + (m2 * 2 + kk) * 512);

        // S half1 — independent of exp(half0)
        floatx4 sb[2][4];
#pragma unroll
        for (int m2 = 0; m2 < 2; ++m2)
#pragma unroll
            for (int nt = 0; nt < 4; ++nt) { floatx4 z = {0.f, 0.f, 0.f, 0.f}; sb[m2][nt] = z; }
#pragma unroll
        for (int kk = 0; kk < 2; ++kk)
#pragma unroll
            for (int m2 = 0; m2 < 2; ++m2)
#pragma unroll
                for (int nt = 0; nt < 4; ++nt)
                    sb[m2][nt] = __builtin_amdgcn_mfma_f32_16x16x32_bf16(kfb[m2][kk], qf[nt][kk], sb[m2][nt], 0, 0, 0);

        // --- half0: exp + P write + PV ---
#pragma unroll
        for (int m2 = 0; m2 < 2; ++m2)
#pragma unroll
            for (int nt = 0; nt < 4; ++nt) {
                float p0 = __builtin_amdgcn_exp2f(sa[m2][nt][0]);
                float p1 = __builtin_amdgcn_exp2f(sa[m2][nt][1]);
                float p2 = __builtin_amdgcn_exp2f(sa[m2][nt][2]);
                float p3 = __builtin_amdgcn_exp2f(sa[m2][nt][3]);
                lsum[nt] += (p0 + p1) + (p2 + p3);
                bf16x4 pk = {(bf16_t)p0, (bf16_t)p1, (bf16_t)p2, (bf16_t)p3};
                *(bf16x4*)&Ps[w * 2560 + (nt * 16 + lm) * 40 + m2 * 16 + g * 4] = pk;
            }
        {
            bf16x8 bp[4];
#pragma unroll
            for (int nt = 0; nt < 4; ++nt)
                bp[nt] = *(const bf16x8*)&Ps[w * 2560 + (nt * 16 + lm) * 40 + g * 8];
#pragma unroll
            for (int dt = 0; dt < 4; ++dt)
#pragma unroll
                for (int nt = 0; nt < 4; ++nt)
                    oacc[dt][nt] = __builtin_amdgcn_mfma_f32_16x16x32_bf16(vfa[dt], bp[nt], oacc[dt][nt], 0, 0, 0);
        }

        // --- half1: exp + P write + PV ---
#pragma unroll
        for (int m2 = 0; m2 < 2; ++m2)
#pragma unroll
            for (int nt = 0; nt < 4; ++nt) {
                float p0 = __builtin_amdgcn_exp2f(sb[m2][nt][0]);
                float p1 = __builtin_amdgcn_exp2f(sb[m2][nt][1]);
                float p2 = __builtin_amdgcn_exp2f(sb[m2][nt][2]);
                float p3 = __builtin_amdgcn_exp2f(sb[m2][nt][3]);
                lsum[nt] += (p0 + p1) + (p2 + p3);
                bf16x4 pk = {(bf16_t)p0, (bf16_t)p1, (bf16_t)p2, (bf16_t)p3};
                *(bf16x4*)&Ps[w * 2560 + (nt * 16 + lm) * 40 + m2 * 16 + g * 4] = pk;
            }
        {
            bf16x8 bp[4];
#pragma unroll
            for (int nt = 0; nt < 4; ++nt)
                bp[nt] = *(const bf16x8*)&Ps[w * 2560 + (nt * 16 + lm) * 40 + g * 8];
#pragma unroll
            for (int dt = 0; dt < 4; ++dt)
#pragma unroll
                for (int nt = 0; nt < 4; ++nt)
                    oacc[dt][nt] = __builtin_amdgcn_mfma_f32_16x16x32_bf16(vfb[dt], bp[nt], oacc[dt][nt], 0, 0, 0);
        }
    }

    // reduce lsum within wave across g-groups
#pragma unroll
    for (int nt = 0; nt < 4; ++nt) {
        float s = lsum[nt];
        s += __shfl_xor(s, 16, 64);
        s += __shfl_xor(s, 32, 64);
        lsum[nt] = s;
    }

    // 4-partial merge through LDS; coalesced Cc stores via Ct
    float linv = 0.f;
#pragma unroll
    for (int p = 0; p < 2; ++p) {
        __syncthreads();
#pragma unroll
        for (int dh = 0; dh < 2; ++dh) {
            int dt = p * 2 + dh;
#pragma unroll
            for (int nt = 0; nt < 4; ++nt)
                *(floatx4*)&Mbuf[w * 2304 + (nt * 16 + lm) * 36 + dh * 16 + g * 4] = oacc[dt][nt];
        }
        if (p == 0 && g == 0)
#pragma unroll
            for (int nt = 0; nt < 4; ++nt)
                Lbuf[w * 64 + nt * 16 + lm] = lsum[nt];
        __syncthreads();
        if (p == 0) {
            float lt = 0.f;
#pragma unroll
            for (int w2 = 0; w2 < 4; ++w2)
                lt += Lbuf[w2 * 64 + w * 16 + lm];
            linv = 1.0f / lt;
        }
#pragma unroll
        for (int cc = 0; cc < 2; ++cc) {
            floatx4 s = {0.f, 0.f, 0.f, 0.f};
#pragma unroll
            for (int w2 = 0; w2 < 4; ++w2)
                s += *(const floatx4*)&Mbuf[w2 * 2304 + (w * 16 + lm) * 36 + cc * 16 + g * 4];
            bf16x4 pk = {(bf16_t)(s[0] * linv), (bf16_t)(s[1] * linv),
                         (bf16_t)(s[2] * linv), (bf16_t)(s[3] * linv)};
            *(bf16x4*)&Ct[w * 640 + lm * 40 + cc * 16 + g * 4] = pk;
        }
        // cooperative row store: 16B/lane, 64B per row
        {
            int row = l >> 2, dp = l & 3;
            bf16x8 v = *(const bf16x8*)&Ct[w * 640 + row * 40 + dp * 8];
            *(bf16x8*)&Cc[((size_t)(b * SEQ + q0 + w * 16 + row)) * DMODEL + h * DKH + p * 32 + dp * 8] = v;
        }
    }
}

// ----------------------------------------------------------------------------
extern "C" void kernel_launch(void* const* d_in, const int* in_sizes, int n_in,
                              void* d_out, int out_size, void* d_ws, size_t ws_size,
                              hipStream_t stream) {
    const float* x  = (const float*)d_in[0];
    const float* Wq = (const float*)d_in[1];
    const float* Wk = (const float*)d_in[2];
    const float* Wv = (const float*)d_in[3];
    const float* Wo = (const float*)d_in[4];

    const size_t NX = (size_t)MROWS * DMODEL;
    const size_t NW = (size_t)DMODEL * DMODEL;
    bf16_t* ws  = (bf16_t*)d_ws;
    bf16_t* xb  = ws;            // x bf16
    bf16_t* Wt  = xb + NX;       // W^T x4 contiguous: q,k,v,o
    bf16_t* Wto = Wt + 3 * NW;
    bf16_t* Qfb = Wt + 4 * NW;   // Q frag-major (B-operand), scaled log2(e)/8
    bf16_t* Kfb = Qfb + NX;      // K frag-major
    bf16_t* Vfb = Kfb + NX;      // V frag-major
    bf16_t* Cc  = Vfb + NX;      // concat

    prep_kernel<<<dim3(32, 32, 5), dim3(32, 8), 0, stream>>>(x, Wq, Wk, Wv, Wo, xb, Wt);

    gemm_qkv_kernel<<<dim3(3 * DMODEL / 128, MROWS / 128), 256, 0, stream>>>(xb, Wt, Qfb, Kfb, Vfb);

    attn_kernel<<<dim3(BATCH * NHEADS, SEQ / 64), 256, 0, stream>>>(Qfb, Kfb, Vfb, Cc);

    gemmO_kernel<<<dim3(DMODEL / 128, MROWS / 64), 256, 0, stream>>>(Cc, Wto, (float*)d_out);
}